// Round 1
// baseline (677.942 us; speedup 1.0000x reference)
//
#include <hip/hip_runtime.h>
#include <hip/hip_bf16.h>
#include <stdint.h>

// Problem: B=32, T=2048, D=1024, U=1024, all fp32 in/out.
// out = [context 32*1024, attention_weights 32*2048]
//
// ws layout:
//   [0, 2MB)           W1t bf16  [U][D]  (transposed W1)
//   [2MB, +128KB)      qp2 fp32  [B][U]  = query@W2 + b2 + b1
//   [2MB+128KB,+256KB) score fp32 [B][T]
#define WS_W1T   0
#define WS_QP2   2097152
#define WS_SCORE (2097152 + 131072)

typedef __attribute__((ext_vector_type(8))) short bf16x8;
typedef __attribute__((ext_vector_type(4))) float f32x4;

__device__ inline uint16_t f2b(float f) {
    __hip_bfloat16 h = __float2bfloat16(f);
    return *reinterpret_cast<uint16_t*>(&h);
}

// ---------------- Kernel 1: W1 [D][U] fp32 -> W1t [U][D] bf16 (+ zero qp2) ----
__global__ __launch_bounds__(256) void k_w1t(const float* __restrict__ W1,
                                             __hip_bfloat16* __restrict__ W1t,
                                             float* __restrict__ qp2) {
    __shared__ __hip_bfloat16 tile[64][72];
    if (blockIdx.x < 128) qp2[blockIdx.x * 256 + threadIdx.x] = 0.f;
    int tu = blockIdx.x & 15, tk = blockIdx.x >> 4;
    int c = threadIdx.x & 63;
    int rb = threadIdx.x >> 6;  // 0..3
    #pragma unroll
    for (int i = 0; i < 16; ++i) {
        int kl = i * 4 + rb;
        tile[kl][c] = __float2bfloat16(W1[(size_t)(tk * 64 + kl) * 1024 + tu * 64 + c]);
    }
    __syncthreads();
    #pragma unroll
    for (int i = 0; i < 16; ++i) {
        int ul = i * 4 + rb;
        W1t[(size_t)(tu * 64 + ul) * 1024 + tk * 64 + c] = tile[c][ul];
    }
}

// ---------------- Kernel 2: qp2[b][u] += sum_d query[b,d]*W2[d,u] (+biases) ---
__global__ __launch_bounds__(256) void k_qp(const float* __restrict__ query,
                                            const float* __restrict__ W2,
                                            const float* __restrict__ b1,
                                            const float* __restrict__ b2,
                                            float* __restrict__ qp2) {
    int b = blockIdx.x >> 3, seg = blockIdx.x & 7;
    int u = threadIdx.x * 4;
    float4 a = {0.f, 0.f, 0.f, 0.f};
    if (seg == 0) {
        a.x = b1[u] + b2[u];     a.y = b1[u+1] + b2[u+1];
        a.z = b1[u+2] + b2[u+2]; a.w = b1[u+3] + b2[u+3];
    }
    const float* q  = query + b * 1024 + seg * 128;
    const float* Wp = W2 + (size_t)seg * 128 * 1024 + u;
    #pragma unroll 8
    for (int d = 0; d < 128; ++d) {
        float qd = q[d];
        float4 wv = *(const float4*)(Wp + (size_t)d * 1024);
        a.x += qd * wv.x; a.y += qd * wv.y; a.z += qd * wv.z; a.w += qd * wv.w;
    }
    float* o = qp2 + b * 1024 + u;
    atomicAdd(o + 0, a.x); atomicAdd(o + 1, a.y);
    atomicAdd(o + 2, a.z); atomicAdd(o + 3, a.w);
}

// ---------------- Kernel 3: fused score = tanh(values@W1 + qp2) @ V ----------
// Grid 1024 = 32 b * 32 row-tiles of 64. Block 256 (4 waves).
// LDS: A resident 64x1024 bf16 (131072 B, XOR-swizzled 16B chunks)
//      W double-buffer 2 x [128 u][64 k] bf16 (32768 B, XOR-swizzled)
__global__ __launch_bounds__(256, 1) void k_score(
        const float* __restrict__ values, const __hip_bfloat16* __restrict__ W1t,
        const float* __restrict__ qp2, const float* __restrict__ V,
        float* __restrict__ score) {
    extern __shared__ char smem[];
    uint16_t* Al = (uint16_t*)smem;               // 65536 elems
    uint16_t* Wl = (uint16_t*)(smem + 131072);    // 2 x 8192 elems

    const int tid = threadIdx.x;
    const int lane = tid & 63, w = tid >> 6;
    const int quad = lane >> 4, l15 = lane & 15;
    const int b = blockIdx.x >> 5, trow0 = (blockIdx.x & 31) << 6;

    // ---- W stage: one 128x64 bf16 tile via global_load_lds (16B/lane) ----
    auto stageW = [&](int g, int buf) {
        int uc = g >> 4, kseg = g & 15;
        const __hip_bfloat16* Wg = W1t + (size_t)(uc * 128) * 1024 + kseg * 64;
        #pragma unroll
        for (int i = 0; i < 4; ++i) {
            int rowbase = w * 8 + i * 32;
            int urow = rowbase + (lane >> 3);
            int cpos = lane & 7;
            int q = cpos ^ (urow & 7);          // logical chunk stored at cpos
            const __hip_bfloat16* src = Wg + (size_t)urow * 1024 + q * 8;
            uint16_t* dst = Wl + buf * 8192 + rowbase * 64;  // uniform base
            __builtin_amdgcn_global_load_lds(
                (const __attribute__((address_space(1))) uint32_t*)src,
                (__attribute__((address_space(3))) uint32_t*)dst, 16, 0, 0);
        }
    };

    stageW(0, 0);

    // ---- A stage: 64 rows x 1024 k fp32 -> bf16 LDS, chunk-XOR swizzle ----
    const float* Ag = values + (size_t)(b * 2048 + trow0) * 1024;
    for (int i = 0; i < 32; ++i) {
        int row = i * 2 + (tid >> 7);
        int q = tid & 127;
        const float* src = Ag + (size_t)row * 1024 + q * 8;
        float4 v0 = *(const float4*)src;
        float4 v1 = *(const float4*)(src + 4);
        int pos = q ^ (row & 7);
        union { uint16_t h[8]; int4 v; } pk;
        pk.h[0] = f2b(v0.x); pk.h[1] = f2b(v0.y); pk.h[2] = f2b(v0.z); pk.h[3] = f2b(v0.w);
        pk.h[4] = f2b(v1.x); pk.h[5] = f2b(v1.y); pk.h[6] = f2b(v1.z); pk.h[7] = f2b(v1.w);
        *(int4*)(Al + (size_t)row * 1024 + pos * 8) = pk.v;
    }
    __syncthreads();   // A ready + W stage 0 ready (vmcnt drained at barrier)

    f32x4 acc[4][2];
    float srow[4][4];
    #pragma unroll
    for (int rt = 0; rt < 4; ++rt) {
        #pragma unroll
        for (int ct = 0; ct < 2; ++ct) acc[rt][ct] = (f32x4){0.f, 0.f, 0.f, 0.f};
        #pragma unroll
        for (int r = 0; r < 4; ++r) srow[rt][r] = 0.f;
    }

    for (int g = 0; g < 128; ++g) {
        int buf = g & 1;
        if (g + 1 < 128) stageW(g + 1, buf ^ 1);

        #pragma unroll
        for (int step = 0; step < 2; ++step) {
            int ks = (g & 15) * 2 + step;       // global k-step 0..31
            bf16x8 af[4];
            #pragma unroll
            for (int rt = 0; rt < 4; ++rt) {
                int row = rt * 16 + l15;
                int lc = ks * 4 + quad;
                int pos = lc ^ (row & 7);
                af[rt] = *(bf16x8*)(Al + (size_t)row * 1024 + pos * 8);
            }
            bf16x8 bfr[2];
            #pragma unroll
            for (int ct = 0; ct < 2; ++ct) {
                int ul = w * 32 + ct * 16 + l15;
                int lcw = step * 4 + quad;
                int pos = lcw ^ (ul & 7);
                bfr[ct] = *(bf16x8*)(Wl + buf * 8192 + ul * 64 + pos * 8);
            }
            #pragma unroll
            for (int rt = 0; rt < 4; ++rt)
                #pragma unroll
                for (int ct = 0; ct < 2; ++ct)
                    acc[rt][ct] = __builtin_amdgcn_mfma_f32_16x16x32_bf16(
                        af[rt], bfr[ct], acc[rt][ct], 0, 0, 0);
        }

        if ((g & 15) == 15) {   // end of u-chunk: tanh + V-dot epilogue
            int uc = g >> 4;
            #pragma unroll
            for (int ct = 0; ct < 2; ++ct) {
                int u = uc * 128 + w * 32 + ct * 16 + l15;
                float qv = qp2[b * 1024 + u];
                float vv = V[u];
                #pragma unroll
                for (int rt = 0; rt < 4; ++rt) {
                    #pragma unroll
                    for (int r = 0; r < 4; ++r) {
                        float x = acc[rt][ct][r] + qv;
                        float e = __expf(2.f * x);
                        float t = 1.f - 2.f * __builtin_amdgcn_rcpf(1.f + e);
                        srow[rt][r] += t * vv;
                    }
                    acc[rt][ct] = (f32x4){0.f, 0.f, 0.f, 0.f};
                }
            }
        }
        __syncthreads();   // drains stage g+1 load; protects buf reuse
    }

    // ---- reduce srow over the 16 lanes sharing a row-group ----
    #pragma unroll
    for (int rt = 0; rt < 4; ++rt)
        #pragma unroll
        for (int r = 0; r < 4; ++r) {
            float s = srow[rt][r];
            s += __shfl_xor(s, 1, 64);
            s += __shfl_xor(s, 2, 64);
            s += __shfl_xor(s, 4, 64);
            s += __shfl_xor(s, 8, 64);
            srow[rt][r] = s;
        }
    float* red = (float*)Wl;   // reuse (all waves past final barrier)
    if (l15 == 0) {
        #pragma unroll
        for (int rt = 0; rt < 4; ++rt)
            #pragma unroll
            for (int r = 0; r < 4; ++r)
                red[w * 64 + rt * 16 + quad * 4 + r] = srow[rt][r];
    }
    __syncthreads();
    if (tid < 64) {
        float s = red[tid] + red[64 + tid] + red[128 + tid] + red[192 + tid];
        score[b * 2048 + trow0 + tid] = s;
    }
}

// ---------------- Kernel 4: softmax over T per b; also zero context ----------
__global__ __launch_bounds__(256) void k_softmax(const float* __restrict__ score,
                                                 float* __restrict__ out) {
    __shared__ float red[8];
    int b = blockIdx.x, tid = threadIdx.x;
    *(float4*)(out + b * 1024 + tid * 4) = make_float4(0.f, 0.f, 0.f, 0.f);
    float s[8]; float m = -1e30f;
    #pragma unroll
    for (int j = 0; j < 8; ++j) {
        s[j] = score[b * 2048 + j * 256 + tid];
        m = fmaxf(m, s[j]);
    }
    for (int off = 32; off; off >>= 1) m = fmaxf(m, __shfl_xor(m, off, 64));
    if ((tid & 63) == 0) red[tid >> 6] = m;
    __syncthreads();
    m = fmaxf(fmaxf(red[0], red[1]), fmaxf(red[2], red[3]));
    float sum = 0.f;
    #pragma unroll
    for (int j = 0; j < 8; ++j) { s[j] = __expf(s[j] - m); sum += s[j]; }
    for (int off = 32; off; off >>= 1) sum += __shfl_xor(sum, off, 64);
    if ((tid & 63) == 0) red[4 + (tid >> 6)] = sum;
    __syncthreads();
    sum = red[4] + red[5] + red[6] + red[7];
    float inv = __builtin_amdgcn_rcpf(sum);
    #pragma unroll
    for (int j = 0; j < 8; ++j)
        out[32768 + b * 2048 + j * 256 + tid] = s[j] * inv;
}

// ---------------- Kernel 5: context[b][d] = sum_t w[b,t]*values[b,t,d] -------
__global__ __launch_bounds__(256) void k_ctx(const float* __restrict__ values,
                                             const float* __restrict__ attw,
                                             float* __restrict__ ctx) {
    __shared__ float wl[128];
    int b = blockIdx.x >> 4, ts = blockIdx.x & 15, tid = threadIdx.x;
    if (tid < 128) wl[tid] = attw[b * 2048 + ts * 128 + tid];
    __syncthreads();
    const float* vb = values + ((size_t)(b * 2048 + ts * 128)) * 1024 + tid * 4;
    float4 a = {0.f, 0.f, 0.f, 0.f};
    #pragma unroll 4
    for (int t = 0; t < 128; ++t) {
        float4 v = *(const float4*)(vb + (size_t)t * 1024);
        float ww = wl[t];
        a.x += ww * v.x; a.y += ww * v.y; a.z += ww * v.z; a.w += ww * v.w;
    }
    float* o = ctx + b * 1024 + tid * 4;
    atomicAdd(o + 0, a.x); atomicAdd(o + 1, a.y);
    atomicAdd(o + 2, a.z); atomicAdd(o + 3, a.w);
}

extern "C" void kernel_launch(void* const* d_in, const int* in_sizes, int n_in,
                              void* d_out, int out_size, void* d_ws, size_t ws_size,
                              hipStream_t stream) {
    const float* query  = (const float*)d_in[0];
    const float* values = (const float*)d_in[1];
    const float* W1 = (const float*)d_in[2];
    const float* b1 = (const float*)d_in[3];
    const float* W2 = (const float*)d_in[4];
    const float* b2 = (const float*)d_in[5];
    const float* V  = (const float*)d_in[6];
    // d_in[7] = bv: adds a constant pre-softmax -> cancels; unused.

    char* ws = (char*)d_ws;
    __hip_bfloat16* W1t = (__hip_bfloat16*)(ws + WS_W1T);
    float* qp2   = (float*)(ws + WS_QP2);
    float* score = (float*)(ws + WS_SCORE);
    float* out = (float*)d_out;

    (void)hipFuncSetAttribute((const void*)k_score,
                              hipFuncAttributeMaxDynamicSharedMemorySize, 163840);

    k_w1t<<<256, 256, 0, stream>>>(W1, W1t, qp2);
    k_qp<<<256, 256, 0, stream>>>(query, W2, b1, b2, qp2);
    k_score<<<1024, 256, 163840, stream>>>(values, W1t, qp2, V, score);
    k_softmax<<<32, 256, 0, stream>>>(score, out);
    k_ctx<<<512, 256, 0, stream>>>(values, out + 32768, out);
}